// Round 2
// baseline (245.379 us; speedup 1.0000x reference)
//
#include <hip/hip_runtime.h>

using short8 = __attribute__((ext_vector_type(8))) short;
using f32x4  = __attribute__((ext_vector_type(4))) float;

__device__ __forceinline__ unsigned short f2bf(float f) {
  unsigned u = __float_as_uint(f);
  u += 0x7fffu + ((u >> 16) & 1u);
  return (unsigned short)(u >> 16);
}
__device__ __forceinline__ float bf2f(unsigned short h) {
  return __uint_as_float(((unsigned)h) << 16);
}

// ---------------- Kernel A: temporal conv over flattened (N*F_IN) axis ----------------
__global__ __launch_bounds__(256) void conv_kernel(const float* __restrict__ x,
                                                   const float* __restrict__ cw,
                                                   const float* __restrict__ cb,
                                                   unsigned short* __restrict__ xt) {
  __shared__ float tile[12][264];
  __shared__ float cws[432];
  __shared__ float cbs[12];
  const int b  = blockIdx.y;
  const int p0 = blockIdx.x << 8;
  const int tid = threadIdx.x;
  for (int i = tid; i < 432; i += 256) cws[i] = cw[i];
  if (tid < 12) cbs[tid] = cb[tid];
  for (int t = 0; t < 12; ++t) {
    for (int i = tid; i < 258; i += 256) {
      int gp = p0 + i - 1;
      float v = 0.f;
      if (gp >= 0 && gp < 2048 * 32) {
        int n = gp >> 5, f = gp & 31;
        v = x[(((size_t)b * 2048 + n) * 12 + t) * 32 + f];
      }
      tile[t][i] = v;
    }
  }
  __syncthreads();
  float acc[12];
#pragma unroll
  for (int to = 0; to < 12; ++to) acc[to] = cbs[to];
#pragma unroll
  for (int ti = 0; ti < 12; ++ti) {
    float x0 = tile[ti][tid], x1 = tile[ti][tid + 1], x2 = tile[ti][tid + 2];
#pragma unroll
    for (int to = 0; to < 12; ++to) {
      const float* wp = &cws[(to * 12 + ti) * 3];
      acc[to] += x0 * wp[0] + x1 * wp[1] + x2 * wp[2];
    }
  }
  const int p = p0 + tid, n = p >> 5, f = p & 31;
  unsigned short* op = xt + ((size_t)b * 2048 + n) * 384 + f;
#pragma unroll
  for (int to = 0; to < 12; ++to) op[to * 32] = f2bf(acc[to]);
}

// ---------------- Transpose f32 [rows][cols] -> bf16 [cols][rows] (for W) ----------------
__global__ __launch_bounds__(256) void transpose_f2b_kernel(const float* __restrict__ in,
                                                            unsigned short* __restrict__ out,
                                                            int rows, int cols) {
  __shared__ float tile[32][33];
  const int r0 = blockIdx.x * 32, c0 = blockIdx.y * 32;
  const int li = threadIdx.x >> 5, ci = threadIdx.x & 31;
#pragma unroll
  for (int p = 0; p < 4; ++p) {
    int r = li + p * 8;
    tile[r][ci] = in[(size_t)(r0 + r) * cols + c0 + ci];
  }
  __syncthreads();
#pragma unroll
  for (int p = 0; p < 4; ++p) {
    int c = li + p * 8;
    out[(size_t)(c0 + c) * rows + r0 + ci] = f2bf(tile[ci][c]);
  }
}

// ---------------- Transpose bf16 [z][rows][cols] -> bf16 [z][cols][rows] (for Wh) ----------------
__global__ __launch_bounds__(256) void transpose_b2b_kernel(const unsigned short* __restrict__ in,
                                                            unsigned short* __restrict__ out,
                                                            int rows, int cols) {
  __shared__ unsigned short tile[32][34];   // stride 34 shorts = 17 words, odd -> conflict-free column reads
  const size_t base = (size_t)blockIdx.z * rows * cols;
  const int r0 = blockIdx.x * 32, c0 = blockIdx.y * 32;
  const int li = threadIdx.x >> 5, ci = threadIdx.x & 31;
#pragma unroll
  for (int p = 0; p < 4; ++p) {
    int r = li + p * 8;
    tile[r][ci] = in[base + (size_t)(r0 + r) * cols + c0 + ci];
  }
  __syncthreads();
#pragma unroll
  for (int p = 0; p < 4; ++p) {
    int c = li + p * 8;
    out[base + (size_t)(c0 + c) * rows + r0 + ci] = tile[ci][c];
  }
}

// ---------------- adj int32 -> bitmask [2048][64] words ----------------
__global__ __launch_bounds__(256) void adjmask_kernel(const int* __restrict__ adj,
                                                      unsigned* __restrict__ adjm) {
  const int wv = (blockIdx.x << 2) + (threadIdx.x >> 6);   // 65536 waves
  const int lane = threadIdx.x & 63;
  const int row = wv >> 5, j0 = (wv & 31) << 6;
  unsigned long long mask = __ballot(adj[(size_t)row * 2048 + j0 + lane] > 0);
  if (lane == 0) {
    adjm[row * 64 + (j0 >> 5)]     = (unsigned)mask;
    adjm[row * 64 + (j0 >> 5) + 1] = (unsigned)(mask >> 32);
  }
}

// ---------------- Kernel B: Wh = xt @ W (bf16 out) + fused f1/f2 ----------------
__global__ __launch_bounds__(384) void gemm_wh_kernel(const unsigned short* __restrict__ xt,
                                                      const unsigned short* __restrict__ Wt,
                                                      const float* __restrict__ a,
                                                      unsigned short* __restrict__ whb,
                                                      float* __restrict__ f1,
                                                      float* __restrict__ f2) {
  __shared__ float s1s[16], s2s[16];
  const int tid = threadIdx.x;
  const int r0 = blockIdx.x << 4;
  const int w = tid >> 6;
  const int lane = tid & 63;
  const int il = lane & 15, kg = lane >> 4;
  if (tid < 16) { s1s[tid] = 0.f; s2s[tid] = 0.f; }
  __syncthreads();
  f32x4 acc[4];
#pragma unroll
  for (int t = 0; t < 4; ++t) acc[t] = (f32x4){0.f, 0.f, 0.f, 0.f};
  const unsigned short* ap = xt + (size_t)(r0 + il) * 384 + kg * 8;
#pragma unroll
  for (int kk = 0; kk < 12; ++kk) {
    short8 af = *reinterpret_cast<const short8*>(ap + kk * 32);
#pragma unroll
    for (int t = 0; t < 4; ++t) {
      int c = (w << 6) + (t << 4) + il;
      short8 bf = *reinterpret_cast<const short8*>(Wt + (size_t)c * 384 + kk * 32 + kg * 8);
      acc[t] = __builtin_amdgcn_mfma_f32_16x16x32_bf16(af, bf, acc[t], 0, 0, 0);
    }
  }
  // fused f1/f2 partials: p[r] = sum_t acc[t][r] * a[col(t)]
  float p1[4] = {0.f, 0.f, 0.f, 0.f}, p2[4] = {0.f, 0.f, 0.f, 0.f};
#pragma unroll
  for (int t = 0; t < 4; ++t) {
    const int c = (w << 6) + (t << 4) + il;
    const float a1v = a[c], a2v = a[384 + c];
#pragma unroll
    for (int r = 0; r < 4; ++r) { p1[r] += acc[t][r] * a1v; p2[r] += acc[t][r] * a2v; }
  }
#pragma unroll
  for (int off = 1; off < 16; off <<= 1) {
#pragma unroll
    for (int r = 0; r < 4; ++r) { p1[r] += __shfl_xor(p1[r], off); p2[r] += __shfl_xor(p2[r], off); }
  }
  if (il == 0) {
#pragma unroll
    for (int r = 0; r < 4; ++r) {
      atomicAdd(&s1s[kg * 4 + r], p1[r]);
      atomicAdd(&s2s[kg * 4 + r], p2[r]);
    }
  }
  // bf16 Wh store
#pragma unroll
  for (int t = 0; t < 4; ++t)
#pragma unroll
    for (int r = 0; r < 4; ++r)
      whb[(size_t)(r0 + kg * 4 + r) * 384 + (w << 6) + (t << 4) + il] = f2bf(acc[t][r]);
  __syncthreads();
  if (tid < 16) { f1[r0 + tid] = s1s[tid]; f2[r0 + tid] = s2s[tid]; }
}

// ---------------- per-batch max of f2 ----------------
__global__ __launch_bounds__(256) void f2max_kernel(const float* __restrict__ f2,
                                                    float* __restrict__ gmax) {
  __shared__ float wm[4];
  const int b = blockIdx.x;
  const int tid = threadIdx.x;
  float m = -3.0e38f;
  for (int i = tid; i < 2048; i += 256) m = fmaxf(m, f2[b * 2048 + i]);
#pragma unroll
  for (int off = 32; off; off >>= 1) m = fmaxf(m, __shfl_xor(m, off));
  if ((tid & 63) == 0) wm[tid >> 6] = m;
  __syncthreads();
  if (tid == 0) gmax[b] = fmaxf(fmaxf(wm[0], wm[1]), fmaxf(wm[2], wm[3]));
}

// ---------------- Kernel E: attention (waves split j-range, LDS combine) ----------------
// block: b(4) x 128 groups of 16 rows; wave w handles j in [w*512, w*512+512)
__global__ __launch_bounds__(256) void attn2_kernel(const float* __restrict__ f1,
                                                    const float* __restrict__ f2,
                                                    const unsigned* __restrict__ adjm,
                                                    const unsigned short* __restrict__ WhT,
                                                    const float* __restrict__ gmax,
                                                    float* __restrict__ out) {
  __shared__ float red[16 * 388];
  __shared__ float dsum[16];
  const int blk = blockIdx.x;
  const int b = blk >> 7;
  const int i0 = (blk & 127) << 4;
  const int tid = threadIdx.x;
  const int w = tid >> 6;
  const int lane = tid & 63;
  const int il = lane & 15, kg = lane >> 4;
  const int ig = i0 + il;

  for (int i = tid; i < 16 * 388; i += 256) red[i] = 0.f;
  if (tid < 16) dsum[tid] = 0.f;
  __syncthreads();

  const float f1v = f1[b * 2048 + ig];
  const float gm = gmax[b];
  const float mz = f1v + gm;
  const float m = mz > 0.f ? mz : 0.2f * mz;     // upper bound of masked row max
  const float* f2b = f2 + b * 2048;
  const unsigned short* whtb = WhT + (size_t)b * 384 * 2048;
  const unsigned* adjr = adjm + ig * 64 + w * 16;

  f32x4 acc[24];
#pragma unroll
  for (int t = 0; t < 24; ++t) acc[t] = (f32x4){0.f, 0.f, 0.f, 0.f};
  float denom = 0.f;

  for (int c = 0; c < 16; ++c) {
    const int jb = (w << 9) + (c << 5) + (kg << 3);
    const unsigned bits = adjr[c] >> (kg * 8);
    float4 g0 = *reinterpret_cast<const float4*>(f2b + jb);
    float4 g1 = *reinterpret_cast<const float4*>(f2b + jb + 4);
    float gv[8] = {g0.x, g0.y, g0.z, g0.w, g1.x, g1.y, g1.z, g1.w};
    short8 af;
    float ssum = 0.f;
#pragma unroll
    for (int u = 0; u < 8; ++u) {
      float z = f1v + gv[u];
      float e = (z > 0.f ? z : 0.2f * z) - m;
      float s = ((bits >> u) & 1u) ? __expf(e) : 0.f;
      unsigned short h = f2bf(s);
      af[u] = (short)h;
      ssum += bf2f(h);
    }
    denom += ssum;
    const unsigned short* bp = whtb + (size_t)il * 2048 + jb;
#pragma unroll
    for (int t = 0; t < 24; ++t) {
      short8 bfr = *reinterpret_cast<const short8*>(bp + (size_t)t * 16 * 2048);
      acc[t] = __builtin_amdgcn_mfma_f32_16x16x32_bf16(af, bfr, acc[t], 0, 0, 0);
    }
  }

  denom += __shfl_xor(denom, 16);
  denom += __shfl_xor(denom, 32);
  if (kg == 0) atomicAdd(&dsum[il], denom);
#pragma unroll
  for (int t = 0; t < 24; ++t)
#pragma unroll
    for (int r = 0; r < 4; ++r)
      atomicAdd(&red[(kg * 4 + r) * 388 + t * 16 + il], acc[t][r]);
  __syncthreads();

  const size_t ob = ((size_t)b * 2048 + i0) * 384;
  for (int i = tid; i < 6144; i += 256) {
    const int row = i / 384, col = i - row * 384;
    float v = red[row * 388 + col] / dsum[row];
    v = v > 0.f ? v : expm1f(v);
    out[ob + i] = v;
  }
}

extern "C" void kernel_launch(void* const* d_in, const int* in_sizes, int n_in,
                              void* d_out, int out_size, void* d_ws, size_t ws_size,
                              hipStream_t stream) {
  const float* x  = (const float*)d_in[0];
  const int* adj  = (const int*)d_in[1];
  const float* W  = (const float*)d_in[2];
  const float* a  = (const float*)d_in[3];
  const float* cw = (const float*)d_in[4];
  const float* cb = (const float*)d_in[5];
  float* out = (float*)d_out;

  char* ws = (char*)d_ws;
  unsigned short* xt  = (unsigned short*)ws; ws += (size_t)3145728 * 2;  // [8192][384] bf16
  unsigned short* Wt  = (unsigned short*)ws; ws += (size_t)147456 * 2;   // [384][384] bf16 (T)
  unsigned short* Whb = (unsigned short*)ws; ws += (size_t)3145728 * 2;  // [8192][384] bf16
  unsigned short* WhT = (unsigned short*)ws; ws += (size_t)3145728 * 2;  // [4][384][2048] bf16
  float* f1           = (float*)ws;          ws += (size_t)8192 * 4;
  float* f2           = (float*)ws;          ws += (size_t)8192 * 4;
  unsigned* adjm      = (unsigned*)ws;       ws += (size_t)2048 * 64 * 4;
  float* gmax         = (float*)ws;          ws += 64;

  conv_kernel<<<dim3(256, 4), 256, 0, stream>>>(x, cw, cb, xt);
  transpose_f2b_kernel<<<dim3(12, 12), 256, 0, stream>>>(W, Wt, 384, 384);
  adjmask_kernel<<<dim3(16384), 256, 0, stream>>>(adj, adjm);
  gemm_wh_kernel<<<dim3(512), 384, 0, stream>>>(xt, Wt, a, Whb, f1, f2);
  f2max_kernel<<<dim3(4), 256, 0, stream>>>(f2, gmax);
  transpose_b2b_kernel<<<dim3(64, 12, 4), 256, 0, stream>>>(Whb, WhT, 2048, 384);
  attn2_kernel<<<dim3(512), 256, 0, stream>>>(f1, f2, adjm, WhT, gmax, out);
}

// Round 4
// 139.099 us; speedup vs baseline: 1.7641x; 1.7641x over previous
//
#include <hip/hip_runtime.h>

using short8 = __attribute__((ext_vector_type(8))) short;
using f32x4  = __attribute__((ext_vector_type(4))) float;

typedef const __attribute__((address_space(1))) void* as1cv;
typedef __attribute__((address_space(3))) void* as3v;

__device__ __forceinline__ unsigned short f2bf(float f) {
  unsigned u = __float_as_uint(f);
  u += 0x7fffu + ((u >> 16) & 1u);
  return (unsigned short)(u >> 16);
}
__device__ __forceinline__ float bf2f(unsigned short h) {
  return __uint_as_float(((unsigned)h) << 16);
}

// ---------------- Kernel A: temporal conv over flattened (N*F_IN) axis ----------------
__global__ __launch_bounds__(256) void conv_kernel(const float* __restrict__ x,
                                                   const float* __restrict__ cw,
                                                   const float* __restrict__ cb,
                                                   unsigned short* __restrict__ xt) {
  __shared__ float tile[12][264];
  __shared__ float cws[432];
  __shared__ float cbs[12];
  const int b  = blockIdx.y;
  const int p0 = blockIdx.x << 8;
  const int tid = threadIdx.x;
  for (int i = tid; i < 432; i += 256) cws[i] = cw[i];
  if (tid < 12) cbs[tid] = cb[tid];
  for (int t = 0; t < 12; ++t) {
    for (int i = tid; i < 258; i += 256) {
      int gp = p0 + i - 1;
      float v = 0.f;
      if (gp >= 0 && gp < 2048 * 32) {
        int n = gp >> 5, f = gp & 31;
        v = x[(((size_t)b * 2048 + n) * 12 + t) * 32 + f];
      }
      tile[t][i] = v;
    }
  }
  __syncthreads();
  float acc[12];
#pragma unroll
  for (int to = 0; to < 12; ++to) acc[to] = cbs[to];
#pragma unroll
  for (int ti = 0; ti < 12; ++ti) {
    float x0 = tile[ti][tid], x1 = tile[ti][tid + 1], x2 = tile[ti][tid + 2];
#pragma unroll
    for (int to = 0; to < 12; ++to) {
      const float* wp = &cws[(to * 12 + ti) * 3];
      acc[to] += x0 * wp[0] + x1 * wp[1] + x2 * wp[2];
    }
  }
  const int p = p0 + tid, n = p >> 5, f = p & 31;
  unsigned short* op = xt + ((size_t)b * 2048 + n) * 384 + f;
#pragma unroll
  for (int to = 0; to < 12; ++to) op[to * 32] = f2bf(acc[to]);
}

// ---------------- Transpose f32 [rows][cols] -> bf16 [cols][rows] (for W) ----------------
__global__ __launch_bounds__(256) void transpose_f2b_kernel(const float* __restrict__ in,
                                                            unsigned short* __restrict__ out,
                                                            int rows, int cols) {
  __shared__ float tile[32][33];
  const int r0 = blockIdx.x * 32, c0 = blockIdx.y * 32;
  const int li = threadIdx.x >> 5, ci = threadIdx.x & 31;
#pragma unroll
  for (int p = 0; p < 4; ++p) {
    int r = li + p * 8;
    tile[r][ci] = in[(size_t)(r0 + r) * cols + c0 + ci];
  }
  __syncthreads();
#pragma unroll
  for (int p = 0; p < 4; ++p) {
    int c = li + p * 8;
    out[(size_t)(c0 + c) * rows + r0 + ci] = f2bf(tile[ci][c]);
  }
}

// ---------------- Transpose bf16 [z][rows][cols] -> bf16 [z][cols][rows] (for Wh) ----------------
__global__ __launch_bounds__(256) void transpose_b2b_kernel(const unsigned short* __restrict__ in,
                                                            unsigned short* __restrict__ out,
                                                            int rows, int cols) {
  __shared__ unsigned short tile[32][34];
  const size_t base = (size_t)blockIdx.z * rows * cols;
  const int r0 = blockIdx.x * 32, c0 = blockIdx.y * 32;
  const int li = threadIdx.x >> 5, ci = threadIdx.x & 31;
#pragma unroll
  for (int p = 0; p < 4; ++p) {
    int r = li + p * 8;
    tile[r][ci] = in[base + (size_t)(r0 + r) * cols + c0 + ci];
  }
  __syncthreads();
#pragma unroll
  for (int p = 0; p < 4; ++p) {
    int c = li + p * 8;
    out[base + (size_t)(c0 + c) * rows + r0 + ci] = tile[ci][c];
  }
}

// ---------------- adj int32 -> bitmask [2048][64] words ----------------
__global__ __launch_bounds__(256) void adjmask_kernel(const int* __restrict__ adj,
                                                      unsigned* __restrict__ adjm) {
  const int wv = (blockIdx.x << 2) + (threadIdx.x >> 6);
  const int lane = threadIdx.x & 63;
  const int row = wv >> 5, j0 = (wv & 31) << 6;
  unsigned long long mask = __ballot(adj[(size_t)row * 2048 + j0 + lane] > 0);
  if (lane == 0) {
    adjm[row * 64 + (j0 >> 5)]     = (unsigned)mask;
    adjm[row * 64 + (j0 >> 5) + 1] = (unsigned)(mask >> 32);
  }
}

// ---------------- Kernel B: Wh = xt @ W (bf16 out) + fused f1/f2 ----------------
__global__ __launch_bounds__(384) void gemm_wh_kernel(const unsigned short* __restrict__ xt,
                                                      const unsigned short* __restrict__ Wt,
                                                      const float* __restrict__ a,
                                                      unsigned short* __restrict__ whb,
                                                      float* __restrict__ f1,
                                                      float* __restrict__ f2) {
  __shared__ float s1s[16], s2s[16];
  const int tid = threadIdx.x;
  const int r0 = blockIdx.x << 4;
  const int w = tid >> 6;
  const int lane = tid & 63;
  const int il = lane & 15, kg = lane >> 4;
  if (tid < 16) { s1s[tid] = 0.f; s2s[tid] = 0.f; }
  __syncthreads();
  f32x4 acc[4];
#pragma unroll
  for (int t = 0; t < 4; ++t) acc[t] = (f32x4){0.f, 0.f, 0.f, 0.f};
  const unsigned short* ap = xt + (size_t)(r0 + il) * 384 + kg * 8;
#pragma unroll
  for (int kk = 0; kk < 12; ++kk) {
    short8 af = *reinterpret_cast<const short8*>(ap + kk * 32);
#pragma unroll
    for (int t = 0; t < 4; ++t) {
      int c = (w << 6) + (t << 4) + il;
      short8 bf = *reinterpret_cast<const short8*>(Wt + (size_t)c * 384 + kk * 32 + kg * 8);
      acc[t] = __builtin_amdgcn_mfma_f32_16x16x32_bf16(af, bf, acc[t], 0, 0, 0);
    }
  }
  float p1[4] = {0.f, 0.f, 0.f, 0.f}, p2[4] = {0.f, 0.f, 0.f, 0.f};
#pragma unroll
  for (int t = 0; t < 4; ++t) {
    const int c = (w << 6) + (t << 4) + il;
    const float a1v = a[c], a2v = a[384 + c];
#pragma unroll
    for (int r = 0; r < 4; ++r) { p1[r] += acc[t][r] * a1v; p2[r] += acc[t][r] * a2v; }
  }
#pragma unroll
  for (int off = 1; off < 16; off <<= 1) {
#pragma unroll
    for (int r = 0; r < 4; ++r) { p1[r] += __shfl_xor(p1[r], off); p2[r] += __shfl_xor(p2[r], off); }
  }
  if (il == 0) {
#pragma unroll
    for (int r = 0; r < 4; ++r) {
      atomicAdd(&s1s[kg * 4 + r], p1[r]);
      atomicAdd(&s2s[kg * 4 + r], p2[r]);
    }
  }
#pragma unroll
  for (int t = 0; t < 4; ++t)
#pragma unroll
    for (int r = 0; r < 4; ++r)
      whb[(size_t)(r0 + kg * 4 + r) * 384 + (w << 6) + (t << 4) + il] = f2bf(acc[t][r]);
  __syncthreads();
  if (tid < 16) { f1[r0 + tid] = s1s[tid]; f2[r0 + tid] = s2s[tid]; }
}

// ---------------- per-batch max of f2 ----------------
__global__ __launch_bounds__(256) void f2max_kernel(const float* __restrict__ f2,
                                                    float* __restrict__ gmax) {
  __shared__ float wm[4];
  const int b = blockIdx.x;
  const int tid = threadIdx.x;
  float m = -3.0e38f;
  for (int i = tid; i < 2048; i += 256) m = fmaxf(m, f2[b * 2048 + i]);
#pragma unroll
  for (int off = 32; off; off >>= 1) m = fmaxf(m, __shfl_xor(m, off));
  if ((tid & 63) == 0) wm[tid >> 6] = m;
  __syncthreads();
  if (tid == 0) gmax[b] = fmaxf(fmaxf(wm[0], wm[1]), fmaxf(wm[2], wm[3]));
}

// ---------------- Kernel E: attention, LDS-staged B, on-the-fly P ----------------
// grid 256: bi&1 = col-half, (bi&7)>>1 = batch, bi>>3 = 64-row group  (XCD-local L2 reuse)
// 8 waves: rg = w>>1 (16-row group), ks = w&1 (K half). Chunk = 32 j's, dbuf per ks stream.
__global__ __launch_bounds__(512) void attn3_kernel(const float* __restrict__ f1,
                                                    const float* __restrict__ f2,
                                                    const unsigned* __restrict__ adjm,
                                                    const unsigned short* __restrict__ WhT,
                                                    const float* __restrict__ gmax,
                                                    float* __restrict__ out) {
  __shared__ __align__(16) char ldsraw[4 * 12288 + 256];   // 4 chunk buffers + dred
  const int bi = blockIdx.x;
  const int b  = (bi & 7) >> 1;
  const int ch = bi & 1;
  const int i0 = (bi >> 3) << 6;
  const int tid = threadIdx.x;
  const int w = tid >> 6, lane = tid & 63;
  const int rg = w >> 1, ks = w & 1;
  const int il = lane & 15, kg = lane >> 4;
  const int ig = i0 + rg * 16 + il;

  const unsigned short* whtb = WhT + (size_t)b * 384 * 2048;
  const float* f2b = f2 + b * 2048;
  const unsigned* adjrow = adjm + (size_t)ig * 64;
  const float f1v = f1[b * 2048 + ig];
  const float gm = gmax[b];
  const float mz = f1v + gm;
  const float m = mz > 0.f ? mz : 0.2f * mz;   // upper bound of masked row max

  // swizzle constants (XOR involution on 16B slots within each col's 64B row)
  const int jsrcC  = (((lane & 3) ^ ((lane >> 2) & 3)) << 4);  // staging source offset
  const int innerC = ((kg ^ (il & 3)) << 4);                    // ds_read offset
  const int sbase = ks * 2;

  f32x4 acc[12];
#pragma unroll
  for (int t = 0; t < 12; ++t) acc[t] = (f32x4){0.f, 0.f, 0.f, 0.f};
  float denom = 0.f;

  // ---- staging: 3 x global_load_lds(16B) per wave per chunk (48 cols x 64B) ----
#define STAGE(BUFIDX, JB)                                                              \
  {                                                                                    \
    _Pragma("unroll")                                                                  \
    for (int g = 0; g < 3; ++g) {                                                      \
      const int cl = rg * 48 + g * 16 + (lane >> 2);                                   \
      const char* gp = (const char*)whtb + (((size_t)(ch * 192 + cl)) << 12) +         \
                       (size_t)(JB) * 2 + jsrcC;                                       \
      char* lp = ldsraw + (BUFIDX) * 12288 + (rg * 48 + g * 16) * 64;                  \
      __builtin_amdgcn_global_load_lds((as1cv)(const void*)gp, (as3v)(void*)lp, 16, 0, 0); \
    }                                                                                  \
  }

  STAGE(sbase, ks * 1024);
  __syncthreads();

  for (int k = 0; k < 32; ++k) {
    const int cur = sbase + (k & 1);
    const int jb = ks * 1024 + k * 32;
    if (k < 31) STAGE(sbase + ((k & 1) ^ 1), jb + 32);

    const char* lb = ldsraw + cur * 12288;
    const unsigned bits8 = (adjrow[jb >> 5] >> (kg * 8)) & 0xffu;
    const float4 g0 = *reinterpret_cast<const float4*>(f2b + jb + kg * 8);
    const float4 g1 = *reinterpret_cast<const float4*>(f2b + jb + kg * 8 + 4);
    const float gv[8] = {g0.x, g0.y, g0.z, g0.w, g1.x, g1.y, g1.z, g1.w};
    short8 af;
    float ssum = 0.f;
#pragma unroll
    for (int u = 0; u < 8; ++u) {
      float z = f1v + gv[u];
      float e = (z > 0.f ? z : 0.2f * z) - m;
      float s = ((bits8 >> u) & 1u) ? __expf(e) : 0.f;
      unsigned short h = f2bf(s);
      af[u] = (short)h;
      ssum += bf2f(h);
    }
    denom += ssum;
#pragma unroll
    for (int t = 0; t < 12; ++t) {
      short8 bfr = *reinterpret_cast<const short8*>(lb + (t * 16 + il) * 64 + innerC);
      acc[t] = __builtin_amdgcn_mfma_f32_16x16x32_bf16(af, bfr, acc[t], 0, 0, 0);
    }
    __syncthreads();
  }

  // ---- epilogue: combine ks halves, normalize, elu, store ----
  denom += __shfl_xor(denom, 16);
  denom += __shfl_xor(denom, 32);          // lane: denom for row il (this ks half)
  float* red  = (float*)ldsraw;            // 16*192 f32 = 12KB, reused per rg round
  float* dred = (float*)(ldsraw + 4 * 12288);
  if (ks == 1 && kg == 0) dred[rg * 16 + il] = denom;
  __syncthreads();
  float dtot = denom;
  if (ks == 0) dtot += dred[rg * 16 + il];  // lane: total denom for row il

  for (int rr = 0; rr < 4; ++rr) {
    if (ks == 1 && rg == rr) {
#pragma unroll
      for (int t = 0; t < 12; ++t)
#pragma unroll
        for (int r = 0; r < 4; ++r)
          red[(kg * 4 + r) * 192 + t * 16 + il] = acc[t][r];
    }
    __syncthreads();
    if (ks == 0 && rg == rr) {
#pragma unroll
      for (int t = 0; t < 12; ++t)
#pragma unroll
        for (int r = 0; r < 4; ++r) {
          float v = acc[t][r] + red[(kg * 4 + r) * 192 + t * 16 + il];
          float dd = __shfl(dtot, kg * 4 + r);
          v /= dd;
          v = v > 0.f ? v : expm1f(v);
          out[((size_t)b * 2048 + i0 + rr * 16 + kg * 4 + r) * 384 + ch * 192 + t * 16 + il] = v;
        }
    }
    __syncthreads();
  }
#undef STAGE
}

extern "C" void kernel_launch(void* const* d_in, const int* in_sizes, int n_in,
                              void* d_out, int out_size, void* d_ws, size_t ws_size,
                              hipStream_t stream) {
  const float* x  = (const float*)d_in[0];
  const int* adj  = (const int*)d_in[1];
  const float* W  = (const float*)d_in[2];
  const float* a  = (const float*)d_in[3];
  const float* cw = (const float*)d_in[4];
  const float* cb = (const float*)d_in[5];
  float* out = (float*)d_out;

  char* ws = (char*)d_ws;
  unsigned short* xt  = (unsigned short*)ws; ws += (size_t)3145728 * 2;  // [8192][384] bf16
  unsigned short* Wt  = (unsigned short*)ws; ws += (size_t)147456 * 2;   // [384][384] bf16 (T)
  unsigned short* Whb = (unsigned short*)ws; ws += (size_t)3145728 * 2;  // [8192][384] bf16
  unsigned short* WhT = (unsigned short*)ws; ws += (size_t)3145728 * 2;  // [4][384][2048] bf16
  float* f1           = (float*)ws;          ws += (size_t)8192 * 4;
  float* f2           = (float*)ws;          ws += (size_t)8192 * 4;
  unsigned* adjm      = (unsigned*)ws;       ws += (size_t)2048 * 64 * 4;
  float* gmax         = (float*)ws;          ws += 64;

  conv_kernel<<<dim3(256, 4), 256, 0, stream>>>(x, cw, cb, xt);
  transpose_f2b_kernel<<<dim3(12, 12), 256, 0, stream>>>(W, Wt, 384, 384);
  adjmask_kernel<<<dim3(16384), 256, 0, stream>>>(adj, adjm);
  gemm_wh_kernel<<<dim3(512), 384, 0, stream>>>(xt, Wt, a, Whb, f1, f2);
  f2max_kernel<<<dim3(4), 256, 0, stream>>>(f2, gmax);
  transpose_b2b_kernel<<<dim3(64, 12, 4), 256, 0, stream>>>(Whb, WhT, 2048, 384);
  attn3_kernel<<<dim3(256), 512, 0, stream>>>(f1, f2, adjm, WhT, gmax, out);
}

// Round 5
// 92.328 us; speedup vs baseline: 2.6577x; 1.5066x over previous
//
#include <hip/hip_runtime.h>

using short8 = __attribute__((ext_vector_type(8))) short;
using f32x4  = __attribute__((ext_vector_type(4))) float;
using f32x16 = __attribute__((ext_vector_type(16))) float;

typedef const __attribute__((address_space(1))) void* as1cv;
typedef __attribute__((address_space(3))) void* as3v;

__device__ __forceinline__ unsigned short f2bf(float f) {
  unsigned u = __float_as_uint(f);
  u += 0x7fffu + ((u >> 16) & 1u);
  return (unsigned short)(u >> 16);
}

// ---------------- Kernel A: temporal conv over flattened (N*F_IN) axis ----------------
__global__ __launch_bounds__(256) void conv_kernel(const float* __restrict__ x,
                                                   const float* __restrict__ cw,
                                                   const float* __restrict__ cb,
                                                   unsigned short* __restrict__ xt) {
  __shared__ float tile[12][264];
  __shared__ float cws[432];
  __shared__ float cbs[12];
  const int b  = blockIdx.y;
  const int p0 = blockIdx.x << 8;
  const int tid = threadIdx.x;
  for (int i = tid; i < 432; i += 256) cws[i] = cw[i];
  if (tid < 12) cbs[tid] = cb[tid];
  for (int t = 0; t < 12; ++t) {
    for (int i = tid; i < 258; i += 256) {
      int gp = p0 + i - 1;
      float v = 0.f;
      if (gp >= 0 && gp < 2048 * 32) {
        int n = gp >> 5, f = gp & 31;
        v = x[(((size_t)b * 2048 + n) * 12 + t) * 32 + f];
      }
      tile[t][i] = v;
    }
  }
  __syncthreads();
  float acc[12];
#pragma unroll
  for (int to = 0; to < 12; ++to) acc[to] = cbs[to];
#pragma unroll
  for (int ti = 0; ti < 12; ++ti) {
    float x0 = tile[ti][tid], x1 = tile[ti][tid + 1], x2 = tile[ti][tid + 2];
#pragma unroll
    for (int to = 0; to < 12; ++to) {
      const float* wp = &cws[(to * 12 + ti) * 3];
      acc[to] += x0 * wp[0] + x1 * wp[1] + x2 * wp[2];
    }
  }
  const int p = p0 + tid, n = p >> 5, f = p & 31;
  unsigned short* op = xt + ((size_t)b * 2048 + n) * 384 + f;
#pragma unroll
  for (int to = 0; to < 12; ++to) op[to * 32] = f2bf(acc[to]);
}

// ---------------- Transpose f32 [rows][cols] -> bf16 [cols][rows] (for W) ----------------
__global__ __launch_bounds__(256) void transpose_f2b_kernel(const float* __restrict__ in,
                                                            unsigned short* __restrict__ out,
                                                            int rows, int cols) {
  __shared__ float tile[32][33];
  const int r0 = blockIdx.x * 32, c0 = blockIdx.y * 32;
  const int li = threadIdx.x >> 5, ci = threadIdx.x & 31;
#pragma unroll
  for (int p = 0; p < 4; ++p) {
    int r = li + p * 8;
    tile[r][ci] = in[(size_t)(r0 + r) * cols + c0 + ci];
  }
  __syncthreads();
#pragma unroll
  for (int p = 0; p < 4; ++p) {
    int c = li + p * 8;
    out[(size_t)(c0 + c) * rows + r0 + ci] = f2bf(tile[ci][c]);
  }
}

// ---------------- Transpose bf16 [z][rows][cols] -> bf16 [z][cols][rows] (for Wh) ----------------
__global__ __launch_bounds__(256) void transpose_b2b_kernel(const unsigned short* __restrict__ in,
                                                            unsigned short* __restrict__ out,
                                                            int rows, int cols) {
  __shared__ unsigned short tile[32][34];
  const size_t base = (size_t)blockIdx.z * rows * cols;
  const int r0 = blockIdx.x * 32, c0 = blockIdx.y * 32;
  const int li = threadIdx.x >> 5, ci = threadIdx.x & 31;
#pragma unroll
  for (int p = 0; p < 4; ++p) {
    int r = li + p * 8;
    tile[r][ci] = in[base + (size_t)(r0 + r) * cols + c0 + ci];
  }
  __syncthreads();
#pragma unroll
  for (int p = 0; p < 4; ++p) {
    int c = li + p * 8;
    out[base + (size_t)(c0 + c) * rows + r0 + ci] = tile[ci][c];
  }
}

// ---------------- adj int32 -> bitmask [2048][64] words ----------------
__global__ __launch_bounds__(256) void adjmask_kernel(const int* __restrict__ adj,
                                                      unsigned* __restrict__ adjm) {
  const int wv = (blockIdx.x << 2) + (threadIdx.x >> 6);
  const int lane = threadIdx.x & 63;
  const int row = wv >> 5, j0 = (wv & 31) << 6;
  unsigned long long mask = __ballot(adj[(size_t)row * 2048 + j0 + lane] > 0);
  if (lane == 0) {
    adjm[row * 64 + (j0 >> 5)]     = (unsigned)mask;
    adjm[row * 64 + (j0 >> 5) + 1] = (unsigned)(mask >> 32);
  }
}

// ---------------- Kernel B: Wh = xt @ W (bf16 out) + fused f1/f2 ----------------
__global__ __launch_bounds__(384) void gemm_wh_kernel(const unsigned short* __restrict__ xt,
                                                      const unsigned short* __restrict__ Wt,
                                                      const float* __restrict__ a,
                                                      unsigned short* __restrict__ whb,
                                                      float* __restrict__ f1,
                                                      float* __restrict__ f2) {
  __shared__ float s1s[16], s2s[16];
  const int tid = threadIdx.x;
  const int r0 = blockIdx.x << 4;
  const int w = tid >> 6;
  const int lane = tid & 63;
  const int il = lane & 15, kg = lane >> 4;
  if (tid < 16) { s1s[tid] = 0.f; s2s[tid] = 0.f; }
  __syncthreads();
  f32x4 acc[4];
#pragma unroll
  for (int t = 0; t < 4; ++t) acc[t] = (f32x4){0.f, 0.f, 0.f, 0.f};
  const unsigned short* ap = xt + (size_t)(r0 + il) * 384 + kg * 8;
#pragma unroll
  for (int kk = 0; kk < 12; ++kk) {
    short8 af = *reinterpret_cast<const short8*>(ap + kk * 32);
#pragma unroll
    for (int t = 0; t < 4; ++t) {
      int c = (w << 6) + (t << 4) + il;
      short8 bf = *reinterpret_cast<const short8*>(Wt + (size_t)c * 384 + kk * 32 + kg * 8);
      acc[t] = __builtin_amdgcn_mfma_f32_16x16x32_bf16(af, bf, acc[t], 0, 0, 0);
    }
  }
  float p1[4] = {0.f, 0.f, 0.f, 0.f}, p2[4] = {0.f, 0.f, 0.f, 0.f};
#pragma unroll
  for (int t = 0; t < 4; ++t) {
    const int c = (w << 6) + (t << 4) + il;
    const float a1v = a[c], a2v = a[384 + c];
#pragma unroll
    for (int r = 0; r < 4; ++r) { p1[r] += acc[t][r] * a1v; p2[r] += acc[t][r] * a2v; }
  }
#pragma unroll
  for (int off = 1; off < 16; off <<= 1) {
#pragma unroll
    for (int r = 0; r < 4; ++r) { p1[r] += __shfl_xor(p1[r], off); p2[r] += __shfl_xor(p2[r], off); }
  }
  if (il == 0) {
#pragma unroll
    for (int r = 0; r < 4; ++r) {
      atomicAdd(&s1s[kg * 4 + r], p1[r]);
      atomicAdd(&s2s[kg * 4 + r], p2[r]);
    }
  }
#pragma unroll
  for (int t = 0; t < 4; ++t)
#pragma unroll
    for (int r = 0; r < 4; ++r)
      whb[(size_t)(r0 + kg * 4 + r) * 384 + (w << 6) + (t << 4) + il] = f2bf(acc[t][r]);
  __syncthreads();
  if (tid < 16) { f1[r0 + tid] = s1s[tid]; f2[r0 + tid] = s2s[tid]; }
}

// ---------------- per-batch max of f2 ----------------
__global__ __launch_bounds__(256) void f2max_kernel(const float* __restrict__ f2,
                                                    float* __restrict__ gmax) {
  __shared__ float wm[4];
  const int b = blockIdx.x;
  const int tid = threadIdx.x;
  float m = -3.0e38f;
  for (int i = tid; i < 2048; i += 256) m = fmaxf(m, f2[b * 2048 + i]);
#pragma unroll
  for (int off = 32; off; off >>= 1) m = fmaxf(m, __shfl_xor(m, off));
  if ((tid & 63) == 0) wm[tid >> 6] = m;
  __syncthreads();
  if (tid == 0) gmax[b] = fmaxf(fmaxf(wm[0], wm[1]), fmaxf(wm[2], wm[3]));
}

// ---------------- Kernel E: attention v4 ----------------
// grid 256: bi&1 = col-half(192), (bi&7)>>1 = batch, bi>>3 = 64-row group (XCD L2 reuse)
// 8 waves = 2 rg (32-row MFMA frags) x 4 ks (512-j streams).
// Per ks stream: 16 chunks of 32 j, triple-buffered 12 KB LDS tiles,
// counted vmcnt(6) + raw s_barrier (1 barrier / chunk). 32x32x16 bf16 MFMA.
#define BUF_BYTES   12288
#define F2LDS_OFF   (12 * BUF_BYTES)            // 147456
#define DRED_OFF    (F2LDS_OFF + 8192)          // 155648
#define ATTN_LDS    (DRED_OFF + 1024)           // 156672 B

__global__ __launch_bounds__(512) void attn4_kernel(const float* __restrict__ f1,
                                                    const float* __restrict__ f2,
                                                    const unsigned* __restrict__ adjm,
                                                    const unsigned short* __restrict__ WhT,
                                                    const float* __restrict__ gmax,
                                                    float* __restrict__ out) {
  __shared__ __align__(16) char lds[ATTN_LDS];
  const int bi = blockIdx.x;
  const int b  = (bi & 7) >> 1;
  const int ch = bi & 1;
  const int i0 = (bi >> 3) << 6;
  const int tid = threadIdx.x;
  const int wv = tid >> 6, lane = tid & 63;
  const int ks = wv & 3, rg = wv >> 2;
  const int l5 = lane & 31, hw = lane >> 5;
  const int ig = i0 + rg * 32 + l5;

  const unsigned short* whtb = WhT + (size_t)b * 384 * 2048;
  const float* f2b = f2 + b * 2048;
  const float f1v = f1[b * 2048 + ig];
  const float gm = gmax[b];
  const float mz = f1v + gm;
  const float m  = fmaxf(mz, 0.2f * mz);   // lrelu(f1+gmax) >= true masked row max
  const float Az = f1v - m;                // u1 = Az + g
  const float Bz = 0.2f * f1v - m;         // u2 = fma(g, 0.2, Bz)

  // preload this lane's adj words (row ig, its ks j-range): 16 words
  unsigned awf[16];
  {
    const uint4* ap = reinterpret_cast<const uint4*>(adjm + (size_t)ig * 64 + ks * 16);
#pragma unroll
    for (int q = 0; q < 4; ++q) {
      uint4 v = ap[q];
      awf[4 * q] = v.x; awf[4 * q + 1] = v.y; awf[4 * q + 2] = v.z; awf[4 * q + 3] = v.w;
    }
  }

  // stage f2 row (2048 f32 = 8 KB) into LDS once
  float* f2lds = (float*)(lds + F2LDS_OFF);
  {
    const float4* src = (const float4*)f2b;
    ((float4*)f2lds)[tid] = src[tid];
  }
  asm volatile("s_waitcnt lgkmcnt(0)" ::: "memory");

  // swizzled staging: linear LDS dest, pre-swizzled global source (rule #21)
#define STAGEA(SLOT, CHUNK)                                                            \
  {                                                                                    \
    const int jbs_ = ks * 512 + (CHUNK) * 32;                                          \
    const int s8_  = (lane & 3) ^ ((lane >> 3) & 3);                                   \
    _Pragma("unroll")                                                                  \
    for (int g = 0; g < 6; ++g) {                                                      \
      const int c_ = rg * 96 + g * 16 + (lane >> 2);                                   \
      const char* gp_ = (const char*)whtb + ((size_t)(ch * 192 + c_) << 12) +          \
                        (size_t)jbs_ * 2 + s8_ * 16;                                   \
      char* lp_ = lds + (ks * 3 + (SLOT)) * BUF_BYTES + (rg * 96 + g * 16) * 64;       \
      __builtin_amdgcn_global_load_lds((as1cv)(const void*)gp_, (as3v)(void*)lp_,      \
                                       16, 0, 0);                                      \
    }                                                                                  \
  }

  const f32x16 zero16 = {0.f,0.f,0.f,0.f,0.f,0.f,0.f,0.f,0.f,0.f,0.f,0.f,0.f,0.f,0.f,0.f};
  f32x16 acc[6];
#pragma unroll
  for (int t = 0; t < 6; ++t) acc[t] = zero16;
  float denom = 0.f;

  STAGEA(0, 0);

#pragma unroll
  for (int k = 0; k < 16; ++k) {
    const int rb = k % 3;
    if (k < 15) {
      STAGEA((k + 1) % 3, k + 1);
      asm volatile("s_waitcnt vmcnt(6)" ::: "memory");
    } else {
      asm volatile("s_waitcnt vmcnt(0)" ::: "memory");
    }
    __builtin_amdgcn_s_barrier();

    const char* buf = lds + (ks * 3 + rb) * BUF_BYTES;
    const int j0 = ks * 512 + k * 32;
    const unsigned word = awf[k];
    const unsigned bA = (word >> (hw * 8)) & 0xffu;          // step 0 bits
    const unsigned bB = (word >> (16 + hw * 8)) & 0xffu;     // step 1 bits

    const float* fp = f2lds + j0 + hw * 8;
    float g0[8], g1[8];
    {
      float4 a0 = *(const float4*)(fp);
      float4 a1 = *(const float4*)(fp + 4);
      float4 c0v = *(const float4*)(fp + 16);
      float4 c1v = *(const float4*)(fp + 20);
      g0[0]=a0.x; g0[1]=a0.y; g0[2]=a0.z; g0[3]=a0.w;
      g0[4]=a1.x; g0[5]=a1.y; g0[6]=a1.z; g0[7]=a1.w;
      g1[0]=c0v.x; g1[1]=c0v.y; g1[2]=c0v.z; g1[3]=c0v.w;
      g1[4]=c1v.x; g1[5]=c1v.y; g1[6]=c1v.z; g1[7]=c1v.w;
    }

    union { unsigned u[4]; short8 s8; } c0, c1;
#pragma unroll
    for (int pr = 0; pr < 8; ++pr) {
      const int s = pr >> 2;
      const int e = (pr & 3) * 2;
      const float glo = s ? g1[e] : g0[e];
      const float ghi = s ? g1[e + 1] : g0[e + 1];
      const unsigned bits = s ? bB : bA;
      float plo = ((bits >> e) & 1u)       ? __expf(fmaxf(Az + glo, fmaf(glo, 0.2f, Bz))) : 0.f;
      float phi = ((bits >> (e + 1)) & 1u) ? __expf(fmaxf(Az + ghi, fmaf(ghi, 0.2f, Bz))) : 0.f;
      const unsigned ulo = __float_as_uint(plo) & 0xffff0000u;   // trunc to bf16
      const unsigned uhi = __float_as_uint(phi) & 0xffff0000u;
      denom += __uint_as_float(ulo) + __uint_as_float(uhi);
      const unsigned pk = uhi | (ulo >> 16);
      if (s == 0) c0.u[pr & 3] = pk; else c1.u[pr & 3] = pk;
    }

#pragma unroll
    for (int t = 0; t < 6; ++t) {
      const int col = t * 32 + l5;
      const int sw = (col >> 1) & 3;
      short8 b0 = *(const short8*)(buf + col * 64 + ((hw ^ sw) << 4));
      short8 b1 = *(const short8*)(buf + col * 64 + (((2 + hw) ^ sw) << 4));
      acc[t] = __builtin_amdgcn_mfma_f32_32x32x16_bf16(c0.s8, b0, acc[t], 0, 0, 0);
      acc[t] = __builtin_amdgcn_mfma_f32_32x32x16_bf16(c1.s8, b1, acc[t], 0, 0, 0);
    }
  }
#undef STAGEA

  // ---- epilogue ----
  __syncthreads();
  float dn = denom + __shfl_xor(denom, 32);
  float* dred = (float*)(lds + DRED_OFF);   // [2 rg][4 ks][32]
  if (hw == 0) dred[(rg * 4 + ks) * 32 + l5] = dn;
  __syncthreads();

  float* red = (float*)lds;                 // [4 ks][32][192] = 96 KB (reuses buffers)
  const size_t obase = ((size_t)b * 2048 + i0) * 384 + ch * 192;
#pragma unroll
  for (int rr = 0; rr < 2; ++rr) {
    if (rg == rr) {
#pragma unroll
      for (int t = 0; t < 6; ++t) {
#pragma unroll
        for (int q = 0; q < 16; ++q) {
          const int r = (q & 3) + 8 * (q >> 2) + 4 * hw;
          red[ks * 6144 + r * 192 + t * 32 + l5] = acc[t][q];
        }
      }
    }
    __syncthreads();
#pragma unroll
    for (int e = 0; e < 12; ++e) {
      const int idx = e * 512 + tid;
      const int r = idx / 192, c = idx - r * 192;
      const float ds = dred[(rr * 4 + 0) * 32 + r] + dred[(rr * 4 + 1) * 32 + r] +
                       dred[(rr * 4 + 2) * 32 + r] + dred[(rr * 4 + 3) * 32 + r];
      float v = red[idx] + red[6144 + idx] + red[12288 + idx] + red[18432 + idx];
      v /= ds;
      v = v > 0.f ? v : expm1f(v);
      out[obase + (size_t)(rr * 32 + r) * 384 + c] = v;
    }
    __syncthreads();
  }
}

extern "C" void kernel_launch(void* const* d_in, const int* in_sizes, int n_in,
                              void* d_out, int out_size, void* d_ws, size_t ws_size,
                              hipStream_t stream) {
  const float* x  = (const float*)d_in[0];
  const int* adj  = (const int*)d_in[1];
  const float* W  = (const float*)d_in[2];
  const float* a  = (const float*)d_in[3];
  const float* cw = (const float*)d_in[4];
  const float* cb = (const float*)d_in[5];
  float* out = (float*)d_out;

  char* ws = (char*)d_ws;
  unsigned short* xt  = (unsigned short*)ws; ws += (size_t)3145728 * 2;  // [8192][384] bf16
  unsigned short* Wt  = (unsigned short*)ws; ws += (size_t)147456 * 2;   // [384][384] bf16 (T)
  unsigned short* Whb = (unsigned short*)ws; ws += (size_t)3145728 * 2;  // [8192][384] bf16
  unsigned short* WhT = (unsigned short*)ws; ws += (size_t)3145728 * 2;  // [4][384][2048] bf16
  float* f1           = (float*)ws;          ws += (size_t)8192 * 4;
  float* f2           = (float*)ws;          ws += (size_t)8192 * 4;
  unsigned* adjm      = (unsigned*)ws;       ws += (size_t)2048 * 64 * 4;
  float* gmax         = (float*)ws;          ws += 64;

  conv_kernel<<<dim3(256, 4), 256, 0, stream>>>(x, cw, cb, xt);
  transpose_f2b_kernel<<<dim3(12, 12), 256, 0, stream>>>(W, Wt, 384, 384);
  adjmask_kernel<<<dim3(16384), 256, 0, stream>>>(adj, adjm);
  gemm_wh_kernel<<<dim3(512), 384, 0, stream>>>(xt, Wt, a, Whb, f1, f2);
  f2max_kernel<<<dim3(4), 256, 0, stream>>>(f2, gmax);
  transpose_b2b_kernel<<<dim3(64, 12, 4), 256, 0, stream>>>(Whb, WhT, 2048, 384);
  attn4_kernel<<<dim3(256), 512, 0, stream>>>(f1, f2, adjm, WhT, gmax, out);
}

// Round 6
// 90.181 us; speedup vs baseline: 2.7210x; 1.0238x over previous
//
#include <hip/hip_runtime.h>

using short8 = __attribute__((ext_vector_type(8))) short;
using f32x4  = __attribute__((ext_vector_type(4))) float;
using f32x16 = __attribute__((ext_vector_type(16))) float;

__device__ __forceinline__ unsigned short f2bf(float f) {
  unsigned u = __float_as_uint(f);
  u += 0x7fffu + ((u >> 16) & 1u);
  return (unsigned short)(u >> 16);
}

// ---------------- Kernel A: temporal conv over flattened (N*F_IN) axis ----------------
__global__ __launch_bounds__(256) void conv_kernel(const float* __restrict__ x,
                                                   const float* __restrict__ cw,
                                                   const float* __restrict__ cb,
                                                   unsigned short* __restrict__ xt) {
  __shared__ float tile[12][264];
  __shared__ float cws[432];
  __shared__ float cbs[12];
  const int b  = blockIdx.y;
  const int p0 = blockIdx.x << 8;
  const int tid = threadIdx.x;
  for (int i = tid; i < 432; i += 256) cws[i] = cw[i];
  if (tid < 12) cbs[tid] = cb[tid];
  for (int t = 0; t < 12; ++t) {
    for (int i = tid; i < 258; i += 256) {
      int gp = p0 + i - 1;
      float v = 0.f;
      if (gp >= 0 && gp < 2048 * 32) {
        int n = gp >> 5, f = gp & 31;
        v = x[(((size_t)b * 2048 + n) * 12 + t) * 32 + f];
      }
      tile[t][i] = v;
    }
  }
  __syncthreads();
  float acc[12];
#pragma unroll
  for (int to = 0; to < 12; ++to) acc[to] = cbs[to];
#pragma unroll
  for (int ti = 0; ti < 12; ++ti) {
    float x0 = tile[ti][tid], x1 = tile[ti][tid + 1], x2 = tile[ti][tid + 2];
#pragma unroll
    for (int to = 0; to < 12; ++to) {
      const float* wp = &cws[(to * 12 + ti) * 3];
      acc[to] += x0 * wp[0] + x1 * wp[1] + x2 * wp[2];
    }
  }
  const int p = p0 + tid, n = p >> 5, f = p & 31;
  unsigned short* op = xt + ((size_t)b * 2048 + n) * 384 + f;
#pragma unroll
  for (int to = 0; to < 12; ++to) op[to * 32] = f2bf(acc[to]);
}

// ---------------- Transpose f32 [rows][cols] -> bf16 [cols][rows] (for W) ----------------
__global__ __launch_bounds__(256) void transpose_f2b_kernel(const float* __restrict__ in,
                                                            unsigned short* __restrict__ out,
                                                            int rows, int cols) {
  __shared__ float tile[32][33];
  const int r0 = blockIdx.x * 32, c0 = blockIdx.y * 32;
  const int li = threadIdx.x >> 5, ci = threadIdx.x & 31;
#pragma unroll
  for (int p = 0; p < 4; ++p) {
    int r = li + p * 8;
    tile[r][ci] = in[(size_t)(r0 + r) * cols + c0 + ci];
  }
  __syncthreads();
#pragma unroll
  for (int p = 0; p < 4; ++p) {
    int c = li + p * 8;
    out[(size_t)(c0 + c) * rows + r0 + ci] = f2bf(tile[ci][c]);
  }
}

// ---------------- adj int32 -> bitmask [2048][64] words ----------------
__global__ __launch_bounds__(256) void adjmask_kernel(const int* __restrict__ adj,
                                                      unsigned* __restrict__ adjm) {
  const int wv = (blockIdx.x << 2) + (threadIdx.x >> 6);
  const int lane = threadIdx.x & 63;
  const int row = wv >> 5, j0 = (wv & 31) << 6;
  unsigned long long mask = __ballot(adj[(size_t)row * 2048 + j0 + lane] > 0);
  if (lane == 0) {
    adjm[row * 64 + (j0 >> 5)]     = (unsigned)mask;
    adjm[row * 64 + (j0 >> 5) + 1] = (unsigned)(mask >> 32);
  }
}

// ---------------- Kernel B: Wh = xt @ W (bf16 out) + fused f1/f2 ----------------
__global__ __launch_bounds__(384) void gemm_wh_kernel(const unsigned short* __restrict__ xt,
                                                      const unsigned short* __restrict__ Wt,
                                                      const float* __restrict__ a,
                                                      unsigned short* __restrict__ whb,
                                                      float* __restrict__ f1,
                                                      float* __restrict__ f2) {
  __shared__ float s1s[16], s2s[16];
  const int tid = threadIdx.x;
  const int r0 = blockIdx.x << 4;
  const int w = tid >> 6;
  const int lane = tid & 63;
  const int il = lane & 15, kg = lane >> 4;
  if (tid < 16) { s1s[tid] = 0.f; s2s[tid] = 0.f; }
  __syncthreads();
  f32x4 acc[4];
#pragma unroll
  for (int t = 0; t < 4; ++t) acc[t] = (f32x4){0.f, 0.f, 0.f, 0.f};
  const unsigned short* ap = xt + (size_t)(r0 + il) * 384 + kg * 8;
#pragma unroll
  for (int kk = 0; kk < 12; ++kk) {
    short8 af = *reinterpret_cast<const short8*>(ap + kk * 32);
#pragma unroll
    for (int t = 0; t < 4; ++t) {
      int c = (w << 6) + (t << 4) + il;
      short8 bf = *reinterpret_cast<const short8*>(Wt + (size_t)c * 384 + kk * 32 + kg * 8);
      acc[t] = __builtin_amdgcn_mfma_f32_16x16x32_bf16(af, bf, acc[t], 0, 0, 0);
    }
  }
  float p1[4] = {0.f, 0.f, 0.f, 0.f}, p2[4] = {0.f, 0.f, 0.f, 0.f};
#pragma unroll
  for (int t = 0; t < 4; ++t) {
    const int c = (w << 6) + (t << 4) + il;
    const float a1v = a[c], a2v = a[384 + c];
#pragma unroll
    for (int r = 0; r < 4; ++r) { p1[r] += acc[t][r] * a1v; p2[r] += acc[t][r] * a2v; }
  }
#pragma unroll
  for (int off = 1; off < 16; off <<= 1) {
#pragma unroll
    for (int r = 0; r < 4; ++r) { p1[r] += __shfl_xor(p1[r], off); p2[r] += __shfl_xor(p2[r], off); }
  }
  if (il == 0) {
#pragma unroll
    for (int r = 0; r < 4; ++r) {
      atomicAdd(&s1s[kg * 4 + r], p1[r]);
      atomicAdd(&s2s[kg * 4 + r], p2[r]);
    }
  }
#pragma unroll
  for (int t = 0; t < 4; ++t)
#pragma unroll
    for (int r = 0; r < 4; ++r)
      whb[(size_t)(r0 + kg * 4 + r) * 384 + (w << 6) + (t << 4) + il] = f2bf(acc[t][r]);
  __syncthreads();
  if (tid < 16) { f1[r0 + tid] = s1s[tid]; f2[r0 + tid] = s2s[tid]; }
}

// ---------------- per-batch max of f2 ----------------
__global__ __launch_bounds__(256) void f2max_kernel(const float* __restrict__ f2,
                                                    float* __restrict__ gmax) {
  __shared__ float wm[4];
  const int b = blockIdx.x;
  const int tid = threadIdx.x;
  float m = -3.0e38f;
  for (int i = tid; i < 2048; i += 256) m = fmaxf(m, f2[b * 2048 + i]);
#pragma unroll
  for (int off = 32; off; off >>= 1) m = fmaxf(m, __shfl_xor(m, off));
  if ((tid & 63) == 0) wm[tid >> 6] = m;
  __syncthreads();
  if (tid == 0) gmax[b] = fmaxf(fmaxf(wm[0], wm[1]), fmaxf(wm[2], wm[3]));
}

// ---------------- pack Whb [b*2048+j][384] -> B-fragment tiles ----------------
// whp[b][ct 12][jc 128][lane 64][8 bf16]: lane l, elem e = Wh[b][jc*16 + (l>>5)*8 + e][ct*32 + (l&31)]
__global__ __launch_bounds__(256) void pack_kernel(const unsigned short* __restrict__ whb,
                                                   unsigned short* __restrict__ whp) {
  __shared__ unsigned short ptile[32][392];
  const int b = blockIdx.y;
  const int jg = blockIdx.x;            // 0..63 : 32 j-rows each
  const int tid = threadIdx.x;
#pragma unroll
  for (int rep = 0; rep < 6; ++rep) {
    const int flat = rep * 256 + tid;   // 0..1535 = 32 rows * 48 segs
    const int row = flat / 48, seg = flat - row * 48;
    *reinterpret_cast<short8*>(&ptile[row][seg * 8]) =
        *reinterpret_cast<const short8*>(whb + ((size_t)(b * 2048 + jg * 32 + row)) * 384 + seg * 8);
  }
  __syncthreads();
#pragma unroll
  for (int rep = 0; rep < 6; ++rep) {
    const int flat = rep * 256 + tid;   // 0..1535 = 24 tiles * 64 lanes
    const int tile = flat >> 6, l = flat & 63;
    const int ct = tile >> 1, jh = tile & 1;
    const int l5 = l & 31, hw2 = l >> 5;
    short8 v;
#pragma unroll
    for (int e = 0; e < 8; ++e)
      v[e] = (short)ptile[jh * 16 + hw2 * 8 + e][ct * 32 + l5];
    *reinterpret_cast<short8*>((char*)whp +
        ((((size_t)b * 12 + ct) * 128 + jg * 2 + jh) << 10) + l * 16) = v;
  }
}

// ---------------- Kernel E: attention v5 — barrier-free main loop, packed B-frags ----------------
// grid 512: bi&1 = ch (192 cols), (bi&7)>>1 = b, bi>>3 = 32-row group. 4 waves = 4 ks (512 j each).
// Per wave: 32 steps of 16 j; B-frags loaded straight to regs (contiguous 1 KB/wave),
// register double-buffered; no LDS/barriers until epilogue. 2 blocks/CU.
__global__ __launch_bounds__(256, 2) void attn5_kernel(const float* __restrict__ f1,
                                                       const float* __restrict__ f2,
                                                       const unsigned* __restrict__ adjm,
                                                       const unsigned short* __restrict__ whp,
                                                       const float* __restrict__ gmax,
                                                       float* __restrict__ out) {
  __shared__ float red[4][32][96];      // 48 KB
  __shared__ float dred[128];
  const int bi = blockIdx.x;
  const int ch = bi & 1;
  const int b  = (bi & 7) >> 1;
  const int i0 = (bi >> 3) << 5;
  const int tid = threadIdx.x;
  const int ks = tid >> 6;
  const int lane = tid & 63;
  const int l5 = lane & 31, hw = lane >> 5;
  const int ig = i0 + l5;

  const float* f2b = f2 + b * 2048;
  const unsigned* adjr = adjm + (size_t)ig * 64 + ks * 16;
  const float f1v = f1[b * 2048 + ig];
  const float gm = gmax[b];
  const float mz = f1v + gm;
  const float m  = fmaxf(mz, 0.2f * mz);   // >= true masked row max (lrelu monotone)
  const float Az = f1v - m;
  const float Bz = 0.2f * f1v - m;

  const char* wbase = (const char*)whp +
      ((((size_t)b * 12 + ch * 6) * 128 + ks * 32) << 10) + lane * 16;

  const f32x16 zero16 = {0.f,0.f,0.f,0.f,0.f,0.f,0.f,0.f,0.f,0.f,0.f,0.f,0.f,0.f,0.f,0.f};
  f32x16 acc[6];
#pragma unroll
  for (int t = 0; t < 6; ++t) acc[t] = zero16;
  float denom = 0.f;

  short8 bA[6], bB[6];
  float4 fA0, fA1, fB0, fB1;

#define LOADB(DST, KK)                                                                  \
  { _Pragma("unroll")                                                                   \
    for (int tt = 0; tt < 6; ++tt)                                                      \
      DST[tt] = *reinterpret_cast<const short8*>(wbase + (((size_t)tt * 128 + (KK)) << 10)); }
#define LOADF(D0, D1, KK)                                                               \
  { const float* fp_ = f2b + ks * 512 + (KK) * 16 + hw * 8;                             \
    D0 = *(const float4*)fp_; D1 = *(const float4*)(fp_ + 4); }

#define PGEMM(BSET, F0, F1, P01)                                                        \
  { const unsigned bits_ = (awC >> ((P01) * 16 + hw * 8)) & 0xffu;                      \
    const float gv[8] = {F0.x, F0.y, F0.z, F0.w, F1.x, F1.y, F1.z, F1.w};               \
    union { unsigned u[4]; short8 s8; } cc;                                             \
    _Pragma("unroll")                                                                   \
    for (int pr = 0; pr < 4; ++pr) {                                                    \
      const int e = pr * 2;                                                             \
      float plo = ((bits_ >> e) & 1u)                                                   \
          ? __expf(fmaxf(Az + gv[e], fmaf(gv[e], 0.2f, Bz))) : 0.f;                     \
      float phi = ((bits_ >> (e + 1)) & 1u)                                             \
          ? __expf(fmaxf(Az + gv[e + 1], fmaf(gv[e + 1], 0.2f, Bz))) : 0.f;             \
      const unsigned ulo = __float_as_uint(plo) & 0xffff0000u;                          \
      const unsigned uhi = __float_as_uint(phi) & 0xffff0000u;                          \
      denom += __uint_as_float(ulo) + __uint_as_float(uhi);                             \
      cc.u[pr] = uhi | (ulo >> 16);                                                     \
    }                                                                                   \
    _Pragma("unroll")                                                                   \
    for (int qq = 0; qq < 6; ++qq)                                                      \
      acc[qq] = __builtin_amdgcn_mfma_f32_32x32x16_bf16(cc.s8, BSET[qq], acc[qq], 0, 0, 0); }

  LOADB(bA, 0); LOADF(fA0, fA1, 0);
  unsigned awC = adjr[0];

  for (int t = 0; t < 16; ++t) {
    const int k0 = 2 * t;
    const unsigned awN = adjr[t < 15 ? t + 1 : 15];
    LOADB(bB, k0 + 1); LOADF(fB0, fB1, k0 + 1);
    PGEMM(bA, fA0, fA1, 0);
    const int kn = (k0 + 2 < 32) ? k0 + 2 : 31;
    LOADB(bA, kn); LOADF(fA0, fA1, kn);
    PGEMM(bB, fB0, fB1, 1);
    awC = awN;
  }
#undef LOADB
#undef LOADF
#undef PGEMM

  // ---- epilogue: combine 4 ks accumulators via LDS, normalize, elu, store ----
  float dn = denom + __shfl_xor(denom, 32);
  if (hw == 0) dred[ks * 32 + l5] = dn;

#pragma unroll
  for (int r = 0; r < 2; ++r) {
#pragma unroll
    for (int t3 = 0; t3 < 3; ++t3) {
      const int t = r * 3 + t3;
#pragma unroll
      for (int q = 0; q < 16; ++q) {
        const int row = (q & 3) + 8 * (q >> 2) + 4 * hw;
        red[ks][row][t3 * 32 + l5] = acc[t][q];
      }
    }
    __syncthreads();
    const size_t ob = ((size_t)b * 2048 + i0) * 384 + ch * 192 + r * 96;
#pragma unroll
    for (int p = 0; p < 12; ++p) {
      const int idx = p * 256 + tid;
      const int row = idx / 96;
      const int c = idx - row * 96;
      float v = red[0][row][c] + red[1][row][c] + red[2][row][c] + red[3][row][c];
      const float d = dred[row] + dred[32 + row] + dred[64 + row] + dred[96 + row];
      v /= d;
      v = v > 0.f ? v : expm1f(v);
      out[ob + (size_t)row * 384 + c] = v;
    }
    __syncthreads();
  }
}

extern "C" void kernel_launch(void* const* d_in, const int* in_sizes, int n_in,
                              void* d_out, int out_size, void* d_ws, size_t ws_size,
                              hipStream_t stream) {
  const float* x  = (const float*)d_in[0];
  const int* adj  = (const int*)d_in[1];
  const float* W  = (const float*)d_in[2];
  const float* a  = (const float*)d_in[3];
  const float* cw = (const float*)d_in[4];
  const float* cb = (const float*)d_in[5];
  float* out = (float*)d_out;

  char* ws = (char*)d_ws;
  unsigned short* xt  = (unsigned short*)ws; ws += (size_t)3145728 * 2;  // [8192][384] bf16
  unsigned short* Wt  = (unsigned short*)ws; ws += (size_t)147456 * 2;   // [384][384] bf16 (T)
  unsigned short* Whb = (unsigned short*)ws; ws += (size_t)3145728 * 2;  // [8192][384] bf16
  unsigned short* whp = (unsigned short*)ws; ws += (size_t)3145728 * 2;  // packed B-frags
  float* f1           = (float*)ws;          ws += (size_t)8192 * 4;
  float* f2           = (float*)ws;          ws += (size_t)8192 * 4;
  unsigned* adjm      = (unsigned*)ws;       ws += (size_t)2048 * 64 * 4;
  float* gmax         = (float*)ws;          ws += 64;

  conv_kernel<<<dim3(256, 4), 256, 0, stream>>>(x, cw, cb, xt);
  transpose_f2b_kernel<<<dim3(12, 12), 256, 0, stream>>>(W, Wt, 384, 384);
  adjmask_kernel<<<dim3(16384), 256, 0, stream>>>(adj, adjm);
  gemm_wh_kernel<<<dim3(512), 384, 0, stream>>>(xt, Wt, a, Whb, f1, f2);
  f2max_kernel<<<dim3(4), 256, 0, stream>>>(f2, gmax);
  pack_kernel<<<dim3(64, 4), 256, 0, stream>>>(Whb, whp);
  attn5_kernel<<<dim3(512), 256, 0, stream>>>(f1, f2, adjm, whp, gmax, out);
}